// Round 10
// baseline (208.964 us; speedup 1.0000x reference)
//
#include <hip/hip_runtime.h>

// SoftAttention: B=4, Q=64, S=1024, H=512, fp32.
// out = [context (B*Q*H)] ++ [weights (B*Q*S)]
// ws: Eq [256*512]f32 @0; sraw4 [4][256][1024]f32 @+512KB;
//     Bhi/Blo @+8.5MB (1MB each); Xhi/Xlo @+10.5MB (4.25MB each);
//     EkT [4][512][1024]f32 @+19MB (8MB); wsum4 [4]f32 after EkT.
//
// R9 measured: -10.2us total (proj 3-buf counted-vmcnt + no-LDS score), but
//   predicted -23; proj'/score' split of remaining ~31us unknown (top-5 shows
//   only the single largest kernel's instances).
// R10: (a) score rep x6 INSTRUMENT (its counters + total-equation give both
//      splits); (b) proj: transpose buffer T aliased into staging LDS ->
//      48KB -> 3 blocks/CU (was 2), better latency hiding; (c) score wsum
//      precomputed per h-quarter in convert_all (removes 4 VALU/g).

constexpr int kB = 4;
constexpr int kQ = 64;
constexpr int kS = 1024;
constexpr int kH = 512;

typedef short bf16x8 __attribute__((ext_vector_type(8)));
typedef float f32x4 __attribute__((ext_vector_type(4)));

__device__ __forceinline__ unsigned bf16rtn_bits(float x) {
  unsigned u = __float_as_uint(x);
  u += 0x7FFFu + ((u >> 16) & 1u);
  return u;  // hi bf16 = u>>16; its f32 bits = u & 0xFFFF0000
}

__device__ __forceinline__ void glds16(const void* g, void* l) {
  __builtin_amdgcn_global_load_lds(
      (__attribute__((address_space(1))) void*)(g),
      (__attribute__((address_space(3))) void*)(l), 16, 0, 0);
}

// ---------------------------------------------------------------------------
// Fused converter. Blocks 0..255: W -> Bhi/Blo. Blocks 256..799: X -> Xhi/Xlo.
// Block 800: wsum4[hq] = sum of we over h-quarter hq.
// ---------------------------------------------------------------------------
__global__ __launch_bounds__(256) void convert_all(
    const float* __restrict__ Wk, const float* __restrict__ Wq,
    const float* __restrict__ key_, const float* __restrict__ query,
    const float* __restrict__ we,
    unsigned short* __restrict__ Bhi, unsigned short* __restrict__ Blo,
    unsigned short* __restrict__ Xhi, unsigned short* __restrict__ Xlo,
    float* __restrict__ wsum4) {
  __shared__ __align__(16) unsigned short LHi[128 * 40];
  __shared__ __align__(16) unsigned short LLo[128 * 40];
  const int bid = blockIdx.x;
  const int t = threadIdx.x;
  if (bid == 800) {
    const int w = t >> 6, ln = t & 63;
    float v = we[w * 128 + ln] + we[w * 128 + 64 + ln];
#pragma unroll
    for (int off = 32; off; off >>= 1) v += __shfl_xor(v, off);
    if (ln == 0) wsum4[w] = v;
    return;
  }
  if (bid < 256) {
    const int gid = bid * 256 + t;
    const int c = gid & 63;
    const int g = (gid >> 6) & 3;
    const int kt = (gid >> 8) & 15;
    const int ct = (gid >> 12) & 7;
    const int mat = gid >> 15;
    const float* W = mat ? Wq : Wk;
    const float* src = W + (size_t)(kt * 32 + g * 8) * kH + ct * 64 + c;
    bf16x8 hv, lv;
#pragma unroll
    for (int j = 0; j < 8; j++) {
      float x = src[(size_t)j * kH];
      unsigned u = bf16rtn_bits(x);
      float hf = __uint_as_float(u & 0xFFFF0000u);
      unsigned v = bf16rtn_bits(x - hf);
      hv[j] = (short)(u >> 16);
      lv[j] = (short)(v >> 16);
    }
    *(bf16x8*)(Bhi + (size_t)gid * 8) = hv;
    *(bf16x8*)(Blo + (size_t)gid * 8) = lv;
    return;
  }
  const int xb = bid - 256;
  const int kt = xb & 15;
  const int rt = xb >> 4;  // 0..33
  const float* X = (rt < 32) ? (key_ + (size_t)rt * 128 * kH)
                             : (query + (size_t)(rt - 32) * 128 * kH);
  const int r = t >> 1, c0 = (t & 1) * 16;
  const float* src = X + (size_t)r * kH + kt * 32 + c0;
  bf16x8 hv0, hv1, lv0, lv1;
#pragma unroll
  for (int i = 0; i < 16; i++) {
    float x = src[i];
    unsigned u = bf16rtn_bits(x);
    float hf = __uint_as_float(u & 0xFFFF0000u);
    unsigned v = bf16rtn_bits(x - hf);
    if (i < 8) { hv0[i] = (short)(u >> 16); lv0[i] = (short)(v >> 16); }
    else       { hv1[i - 8] = (short)(u >> 16); lv1[i - 8] = (short)(v >> 16); }
  }
  *(bf16x8*)&LHi[r * 40 + c0] = hv0;
  *(bf16x8*)&LHi[r * 40 + c0 + 8] = hv1;
  *(bf16x8*)&LLo[r * 40 + c0] = lv0;
  *(bf16x8*)&LLo[r * 40 + c0 + 8] = lv1;
  __syncthreads();
  const size_t obase = (size_t)(rt * 16 + kt) * 512 * 8;
#pragma unroll
  for (int p = 0; p < 2; p++) {
    const int s = t + p * 256;
    const int rr = s & 127, g = s >> 7;
    *(uint4*)(Xhi + obase + (size_t)s * 8) = *(const uint4*)&LHi[rr * 40 + g * 8];
    *(uint4*)(Xlo + obase + (size_t)s * 8) = *(const uint4*)&LLo[rr * 40 + g * 8];
  }
}

// ---------------------------------------------------------------------------
// Projection via MFMA. E = exp(2*(X @ W + bias)).
// 64x64 tile, 256 thr = 4 waves, 12 MFMA/K-step, BK=32. 3-buffer staging in
// one 48KB SMEM block (counted s_waitcnt vmcnt(4) + raw s_barrier, never
// drained in-loop); transpose buffer T ALIASES the staging LDS (dead after
// K-loop) -> 48KB total -> 3 blocks/CU. grid (8,68) XCD-swizzled.
// ---------------------------------------------------------------------------
__global__ __launch_bounds__(256) void proj_mfma(
    const unsigned short* __restrict__ Xhi, const unsigned short* __restrict__ Xlo,
    const unsigned short* __restrict__ Bhi, const unsigned short* __restrict__ Blo,
    const float* __restrict__ bk, const float* __restrict__ bq,
    float* __restrict__ EkT, float* __restrict__ Eq) {
  __shared__ __align__(16) unsigned short SMEM[3 * 8192];  // 48KB
  // buffer rb: Ahi @ rb*8192, Alo @ +2048, Bhi @ +4096, Blo @ +6144 (ushorts)

  const int bid = blockIdx.y * 8 + blockIdx.x;
  int ct, rt;
  if (bid < 512) {
    ct = (bid >> 3) & 7;
    rt = (bid & 7) + 8 * (bid >> 6);
  } else {
    const int tb = bid - 512;
    ct = tb >> 2;
    rt = 64 + (tb & 3);
  }

  const int mat = (rt >= 64) ? 1 : 0;
  const float* bias = mat ? bq : bk;

  const int t = threadIdx.x;
  const int rt128 = rt >> 1, hhalf = rt & 1;
  const int ga_slot = ((t >> 6) << 7) + (hhalf << 6) + (t & 63);
  const unsigned short* gah = Xhi + ((size_t)(rt128 * 16) * 512 + ga_slot) * 8;
  const unsigned short* gal = Xlo + ((size_t)(rt128 * 16) * 512 + ga_slot) * 8;
  const unsigned short* gbh = Bhi + (((size_t)(mat * 8 + ct) * 16) * 256 + t) * 8;
  const unsigned short* gbl = Blo + (((size_t)(mat * 8 + ct) * 16) * 256 + t) * 8;

  auto stage = [&](int buf, int kt2) {
    unsigned short* base = SMEM + buf * 8192;
    glds16(gah + (size_t)kt2 * 512 * 8, base + t * 8);
    glds16(gal + (size_t)kt2 * 512 * 8, base + 2048 + t * 8);
    glds16(gbh + (size_t)kt2 * 256 * 8, base + 4096 + t * 8);
    glds16(gbl + (size_t)kt2 * 256 * 8, base + 6144 + t * 8);
  };

  const int l = t & 63, lg = l >> 4, lr = l & 15;
  const int wv = t >> 6, wm = wv >> 1, wn = wv & 1;
  const int oa0 = (lg * 64 + wm * 32 + lr) * 8;
  const int ob0 = (lg * 64 + wn * 32 + lr) * 8;

  f32x4 acc[2][2];
#pragma unroll
  for (int m = 0; m < 2; m++)
#pragma unroll
    for (int n = 0; n < 2; n++) acc[m][n] = {0.f, 0.f, 0.f, 0.f};

  stage(0, 0);
  stage(1, 1);

#pragma unroll
  for (int kt2 = 0; kt2 < 16; kt2++) {
    if (kt2 < 15) asm volatile("s_waitcnt vmcnt(4)" ::: "memory");
    else          asm volatile("s_waitcnt vmcnt(0)" ::: "memory");
    __builtin_amdgcn_s_barrier();
    __builtin_amdgcn_sched_barrier(0);

    const unsigned short* base = SMEM + (kt2 % 3) * 8192;
    bf16x8 ah[2], al[2], bh[2], bl[2];
#pragma unroll
    for (int m = 0; m < 2; m++) {
      ah[m] = *(const bf16x8*)(base + oa0 + m * 128);
      al[m] = *(const bf16x8*)(base + 2048 + oa0 + m * 128);
    }
#pragma unroll
    for (int n = 0; n < 2; n++) {
      bh[n] = *(const bf16x8*)(base + 4096 + ob0 + n * 128);
      bl[n] = *(const bf16x8*)(base + 6144 + ob0 + n * 128);
    }
    if (kt2 < 14) stage((kt2 + 2) % 3, kt2 + 2);  // overlaps MFMAs below
#pragma unroll
    for (int m = 0; m < 2; m++)
#pragma unroll
      for (int n = 0; n < 2; n++) {
        acc[m][n] = __builtin_amdgcn_mfma_f32_16x16x32_bf16(ah[m], bh[n], acc[m][n], 0, 0, 0);
        acc[m][n] = __builtin_amdgcn_mfma_f32_16x16x32_bf16(al[m], bh[n], acc[m][n], 0, 0, 0);
        acc[m][n] = __builtin_amdgcn_mfma_f32_16x16x32_bf16(ah[m], bl[n], acc[m][n], 0, 0, 0);
      }
    __builtin_amdgcn_sched_barrier(0);
  }

  const int colL = wn * 32 + lr;
  const int col0 = ct * 64 + colL;
  const float b0 = bias[col0];
  const float b1 = bias[col0 + 16];

  if (mat == 0) {
    __syncthreads();  // staging LDS dead everywhere -> safe to alias as T
    float (*T)[65] = (float(*)[65])SMEM;  // 64x65 f32 = 16.6KB < 48KB
#pragma unroll
    for (int m = 0; m < 2; m++) {
      const int row0 = wm * 32 + m * 16 + lg * 4;
#pragma unroll
      for (int jj = 0; jj < 4; jj++) {
        T[row0 + jj][colL]      = __expf(2.f * (acc[m][0][jj] + b0));
        T[row0 + jj][colL + 16] = __expf(2.f * (acc[m][1][jj] + b1));
      }
    }
    __syncthreads();
    const int sl = t & 63;
    const int cb = (t >> 6) * 16;
    const int R = rt * 64 + sl;
    const int bb = R >> 10, ss = R & 1023;
    float* outp = EkT + ((size_t)(bb * kH + ct * 64)) * kS + ss;
#pragma unroll
    for (int i = 0; i < 16; i++)
      outp[(size_t)(cb + i) * kS] = T[sl][cb + i];
  } else {
    float* Y = Eq + (size_t)(rt - 64) * 64 * kH;
#pragma unroll
    for (int m = 0; m < 2; m++) {
      const int row0 = wm * 32 + m * 16 + lg * 4;
#pragma unroll
      for (int jj = 0; jj < 4; jj++) {
        float* y = Y + (size_t)(row0 + jj) * kH;
        y[col0]      = __expf(2.f * (acc[m][0][jj] + b0));
        y[col0 + 16] = __expf(2.f * (acc[m][1][jj] + b1));
      }
    }
  }
}

// ---------------------------------------------------------------------------
// Scores (partials) -> sraw4[hq][bq][s].  No LDS, no barriers.  REP x6 for
// measurement (idempotent; base time = shown/6).
// Unit = wave = (b, q-pair, 64 s, 128 h-quarter): 8192 waves.
// wsum read precomputed from wsum4[hq] (scalar).
// ---------------------------------------------------------------------------
__global__ __launch_bounds__(128) void score_kernel(
    const float* __restrict__ Eq, const float* __restrict__ EkT,
    const float* __restrict__ wsum4, const float* __restrict__ we,
    float* __restrict__ sraw4) {
  const int t = threadIdx.x, lane = t & 63;
  const int wvu = __builtin_amdgcn_readfirstlane(t >> 6);
  const int u = blockIdx.x * 2 + wvu;
  const int hq = u & 3, st = (u >> 2) & 15, qp = (u >> 6) & 31, b = u >> 11;
  const int s = st * 64 + lane;
  const int q0g = b * kQ + qp * 2;
  const int h0 = hq * 128;

  const float4* w4 = (const float4*)(we + h0);
  const float4* qa4 = (const float4*)(Eq + (size_t)q0g * kH + h0);
  const float4* qb4 = (const float4*)(Eq + (size_t)(q0g + 1) * kH + h0);
  const float* ek = EkT + ((size_t)(b * kH + h0)) * kS + s;
  const float wsum = wsum4[hq];
  float* plane = sraw4 + (size_t)hq * kB * kQ * kS;

#pragma unroll 1
  for (int rep = 0; rep < 6; ++rep) {
    asm volatile("" ::: "memory");
    float accA = 0.f, accB = 0.f;
#pragma unroll 4
    for (int g = 0; g < 32; g++) {
      const float4 w = w4[g];
      const float4 qa = qa4[g];
      const float4 qb = qb4[g];
      const float e0 = ek[(size_t)(4 * g + 0) * kS];
      const float e1 = ek[(size_t)(4 * g + 1) * kS];
      const float e2 = ek[(size_t)(4 * g + 2) * kS];
      const float e3 = ek[(size_t)(4 * g + 3) * kS];
      {
        float a1 = fmaf(qa.x, e0, 1.f), c1 = fmaf(qa.y, e1, 1.f);
        accA = fmaf(fmaf(w.y, a1, w.x * c1), __builtin_amdgcn_rcpf(a1 * c1), accA);
        float a2 = fmaf(qa.z, e2, 1.f), c2 = fmaf(qa.w, e3, 1.f);
        accA = fmaf(fmaf(w.w, a2, w.z * c2), __builtin_amdgcn_rcpf(a2 * c2), accA);
      }
      {
        float a1 = fmaf(qb.x, e0, 1.f), c1 = fmaf(qb.y, e1, 1.f);
        accB = fmaf(fmaf(w.y, a1, w.x * c1), __builtin_amdgcn_rcpf(a1 * c1), accB);
        float a2 = fmaf(qb.z, e2, 1.f), c2 = fmaf(qb.w, e3, 1.f);
        accB = fmaf(fmaf(w.w, a2, w.z * c2), __builtin_amdgcn_rcpf(a2 * c2), accB);
      }
    }
    plane[(size_t)(q0g + 0) * kS + s] = fmaf(-2.f, accA, wsum);
    plane[(size_t)(q0g + 1) * kS + s] = fmaf(-2.f, accB, wsum);
  }
}

// ---------------------------------------------------------------------------
// Fused softmax + context + reduce (unchanged from R9).
// ---------------------------------------------------------------------------
__global__ __launch_bounds__(256) void ctx_fused(
    const float* __restrict__ sraw4, const float* __restrict__ value,
    float* __restrict__ wout, float* __restrict__ ctx) {
  __shared__ __align__(16) float wt[4][1024];
  __shared__ __align__(16) float parts[4][4][128];
  const int bid = blockIdx.x;
  const int qc = bid >> 4, b = (bid >> 2) & 3, hc = bid & 3;
  const int t = threadIdx.x, wv = t >> 6, lane = t & 63;
  const int grow = b * kQ + qc * 4 + wv;

  const size_t plane = (size_t)kB * kQ * kS / 4;
  const float4* r0 = (const float4*)(sraw4) + (size_t)grow * (kS / 4);
  const float4* r1 = r0 + plane;
  const float4* r2 = r1 + plane;
  const float4* r3 = r2 + plane;
  float4 v[4];
#pragma unroll
  for (int j = 0; j < 4; j++) {
    const int idx = lane + 64 * j;
    float4 p0 = r0[idx], p1 = r1[idx], p2 = r2[idx], p3 = r3[idx];
    v[j].x = (p0.x + p1.x) + (p2.x + p3.x);
    v[j].y = (p0.y + p1.y) + (p2.y + p3.y);
    v[j].z = (p0.z + p1.z) + (p2.z + p3.z);
    v[j].w = (p0.w + p1.w) + (p2.w + p3.w);
  }
  float m = -1e30f;
#pragma unroll
  for (int j = 0; j < 4; j++)
    m = fmaxf(m, fmaxf(fmaxf(v[j].x, v[j].y), fmaxf(v[j].z, v[j].w)));
#pragma unroll
  for (int off = 32; off; off >>= 1) m = fmaxf(m, __shfl_xor(m, off));
  float sum = 0.f;
#pragma unroll
  for (int j = 0; j < 4; j++) {
    v[j].x = __expf(v[j].x - m); v[j].y = __expf(v[j].y - m);
    v[j].z = __expf(v[j].z - m); v[j].w = __expf(v[j].w - m);
    sum += v[j].x + v[j].y + v[j].z + v[j].w;
  }
#pragma unroll
  for (int off = 32; off; off >>= 1) sum += __shfl_xor(sum, off);
  const float inv = 1.f / sum;
  float4* wrow = (float4*)&wt[wv][0];
  float4* gw = (float4*)(wout + (size_t)grow * kS);
#pragma unroll
  for (int j = 0; j < 4; j++) {
    v[j].x *= inv; v[j].y *= inv; v[j].z *= inv; v[j].w *= inv;
    wrow[lane + 64 * j] = v[j];
    if (hc == 0) gw[lane + 64 * j] = v[j];
  }
  __syncthreads();

  const float* vbase =
      value + ((size_t)b * kS + wv * 256) * kH + hc * 128 + lane * 2;
  float2 acc[4];
#pragma unroll
  for (int q = 0; q < 4; q++) acc[q] = {0.f, 0.f};
#pragma unroll 2
  for (int s4 = 0; s4 < 64; s4++) {
    float4 wq[4];
#pragma unroll
    for (int q = 0; q < 4; q++)
      wq[q] = *(const float4*)&wt[q][wv * 256 + s4 * 4];
#pragma unroll
    for (int uu = 0; uu < 4; uu++) {
      const float2 vv = *(const float2*)(vbase + (size_t)(s4 * 4 + uu) * kH);
      const float w0 = ((const float*)&wq[0])[uu];
      const float w1 = ((const float*)&wq[1])[uu];
      const float w2 = ((const float*)&wq[2])[uu];
      const float w3 = ((const float*)&wq[3])[uu];
      acc[0].x = fmaf(w0, vv.x, acc[0].x); acc[0].y = fmaf(w0, vv.y, acc[0].y);
      acc[1].x = fmaf(w1, vv.x, acc[1].x); acc[1].y = fmaf(w1, vv.y, acc[1].y);
      acc[2].x = fmaf(w2, vv.x, acc[2].x); acc[2].y = fmaf(w2, vv.y, acc[2].y);
      acc[3].x = fmaf(w3, vv.x, acc[3].x); acc[3].y = fmaf(w3, vv.y, acc[3].y);
    }
  }
#pragma unroll
  for (int q = 0; q < 4; q++)
    *(float2*)&parts[wv][q][lane * 2] = acc[q];
  __syncthreads();

  const int q = t >> 6, hp = t & 63;
  float2 r = {0.f, 0.f};
#pragma unroll
  for (int w = 0; w < 4; w++) {
    const float2 p2 = *(const float2*)&parts[w][q][hp * 2];
    r.x += p2.x; r.y += p2.y;
  }
  *(float2*)(ctx + (size_t)(b * kQ + qc * 4 + q) * kH + hc * 128 + hp * 2) = r;
}

extern "C" void kernel_launch(void* const* d_in, const int* in_sizes, int n_in,
                              void* d_out, int out_size, void* d_ws,
                              size_t ws_size, hipStream_t stream) {
  const float* query = (const float*)d_in[0];
  const float* key_  = (const float*)d_in[1];
  const float* value = (const float*)d_in[2];
  const float* Wq    = (const float*)d_in[3];
  const float* bq    = (const float*)d_in[4];
  const float* Wk    = (const float*)d_in[5];
  const float* bk    = (const float*)d_in[6];
  const float* we    = (const float*)d_in[7];
  // be (d_in[8]) cancels in softmax.

  float* ctx  = (float*)d_out;                         // [256*512]
  float* wout = (float*)d_out + (size_t)kB * kQ * kH;  // [256*1024]

  float* Eq    = (float*)d_ws;                          // 512 KB
  float* sraw4 = Eq + (size_t)kB * kQ * kH;             // 4 MB
  unsigned short* Bhi =
      (unsigned short*)((char*)d_ws + (size_t)(kB * kQ * kH + kB * kS * kH) * 4);
  unsigned short* Blo = Bhi + (size_t)2 * 8 * 16 * 256 * 8;  // +1MB
  unsigned short* Xhi = Blo + (size_t)2 * 8 * 16 * 256 * 8;  // +1MB
  unsigned short* Xlo = Xhi + (size_t)34 * 16 * 512 * 8;     // +4.25MB
  float* EkT = (float*)(Xlo + (size_t)34 * 16 * 512 * 8);    // +4.25MB -> 8MB
  float* wsum4 = EkT + (size_t)4 * 512 * 1024;               // 16B

  convert_all<<<801, 256, 0, stream>>>(Wk, Wq, key_, query, we, Bhi, Blo, Xhi,
                                       Xlo, wsum4);
  proj_mfma<<<dim3(8, 68), 256, 0, stream>>>(Xhi, Xlo, Bhi, Blo, bk, bq, EkT, Eq);
  score_kernel<<<4096, 128, 0, stream>>>(Eq, EkT, wsum4, we, sraw4);
  ctx_fused<<<256, 256, 0, stream>>>(sraw4, value, wout, ctx);
}

// Round 12
// 134.781 us; speedup vs baseline: 1.5504x; 1.5504x over previous
//
#include <hip/hip_runtime.h>

// SoftAttention: B=4, Q=64, S=1024, H=512, fp32.
// out = [context (B*Q*H)] ++ [weights (B*Q*S)]
// ws: Eq [256*512]f32 @0; sraw4 [4][256][1024]f32 @+512KB;
//     Bhi/Blo @+8.5MB (1MB each); Xhi/Xlo @+10.5MB (4.25MB each);
//     EkT [4][512][1024]f32 @+19MB (8MB); wsum4 [4]f32 after EkT.
//
// R12 = R11 RESUBMIT (R11 failed on container infra, not kernel; R5 precedent).
// R10 measured: score marginal 16.9us (VALUBusy 63, Occ 49 <- 128-thr
//   workgroup/CU cap), EkT 97% cache-hit; deflated R10 state ~124us.
// R11/R12: (a) score rep removed (lock in R10 state); (b) score blocks
//   128->256 (grid 2048, u = bid*4+wave; 4 waves of a block = 4 h-quarters
//   of one (b,qp,st) -> shared Eq rows in K$) -> ~32 waves/CU.

constexpr int kB = 4;
constexpr int kQ = 64;
constexpr int kS = 1024;
constexpr int kH = 512;

typedef short bf16x8 __attribute__((ext_vector_type(8)));
typedef float f32x4 __attribute__((ext_vector_type(4)));

__device__ __forceinline__ unsigned bf16rtn_bits(float x) {
  unsigned u = __float_as_uint(x);
  u += 0x7FFFu + ((u >> 16) & 1u);
  return u;  // hi bf16 = u>>16; its f32 bits = u & 0xFFFF0000
}

__device__ __forceinline__ void glds16(const void* g, void* l) {
  __builtin_amdgcn_global_load_lds(
      (__attribute__((address_space(1))) void*)(g),
      (__attribute__((address_space(3))) void*)(l), 16, 0, 0);
}

// ---------------------------------------------------------------------------
// Fused converter. Blocks 0..255: W -> Bhi/Blo. Blocks 256..799: X -> Xhi/Xlo.
// Block 800: wsum4[hq] = sum of we over h-quarter hq.
// ---------------------------------------------------------------------------
__global__ __launch_bounds__(256) void convert_all(
    const float* __restrict__ Wk, const float* __restrict__ Wq,
    const float* __restrict__ key_, const float* __restrict__ query,
    const float* __restrict__ we,
    unsigned short* __restrict__ Bhi, unsigned short* __restrict__ Blo,
    unsigned short* __restrict__ Xhi, unsigned short* __restrict__ Xlo,
    float* __restrict__ wsum4) {
  __shared__ __align__(16) unsigned short LHi[128 * 40];
  __shared__ __align__(16) unsigned short LLo[128 * 40];
  const int bid = blockIdx.x;
  const int t = threadIdx.x;
  if (bid == 800) {
    const int w = t >> 6, ln = t & 63;
    float v = we[w * 128 + ln] + we[w * 128 + 64 + ln];
#pragma unroll
    for (int off = 32; off; off >>= 1) v += __shfl_xor(v, off);
    if (ln == 0) wsum4[w] = v;
    return;
  }
  if (bid < 256) {
    const int gid = bid * 256 + t;
    const int c = gid & 63;
    const int g = (gid >> 6) & 3;
    const int kt = (gid >> 8) & 15;
    const int ct = (gid >> 12) & 7;
    const int mat = gid >> 15;
    const float* W = mat ? Wq : Wk;
    const float* src = W + (size_t)(kt * 32 + g * 8) * kH + ct * 64 + c;
    bf16x8 hv, lv;
#pragma unroll
    for (int j = 0; j < 8; j++) {
      float x = src[(size_t)j * kH];
      unsigned u = bf16rtn_bits(x);
      float hf = __uint_as_float(u & 0xFFFF0000u);
      unsigned v = bf16rtn_bits(x - hf);
      hv[j] = (short)(u >> 16);
      lv[j] = (short)(v >> 16);
    }
    *(bf16x8*)(Bhi + (size_t)gid * 8) = hv;
    *(bf16x8*)(Blo + (size_t)gid * 8) = lv;
    return;
  }
  const int xb = bid - 256;
  const int kt = xb & 15;
  const int rt = xb >> 4;  // 0..33
  const float* X = (rt < 32) ? (key_ + (size_t)rt * 128 * kH)
                             : (query + (size_t)(rt - 32) * 128 * kH);
  const int r = t >> 1, c0 = (t & 1) * 16;
  const float* src = X + (size_t)r * kH + kt * 32 + c0;
  bf16x8 hv0, hv1, lv0, lv1;
#pragma unroll
  for (int i = 0; i < 16; i++) {
    float x = src[i];
    unsigned u = bf16rtn_bits(x);
    float hf = __uint_as_float(u & 0xFFFF0000u);
    unsigned v = bf16rtn_bits(x - hf);
    if (i < 8) { hv0[i] = (short)(u >> 16); lv0[i] = (short)(v >> 16); }
    else       { hv1[i - 8] = (short)(u >> 16); lv1[i - 8] = (short)(v >> 16); }
  }
  *(bf16x8*)&LHi[r * 40 + c0] = hv0;
  *(bf16x8*)&LHi[r * 40 + c0 + 8] = hv1;
  *(bf16x8*)&LLo[r * 40 + c0] = lv0;
  *(bf16x8*)&LLo[r * 40 + c0 + 8] = lv1;
  __syncthreads();
  const size_t obase = (size_t)(rt * 16 + kt) * 512 * 8;
#pragma unroll
  for (int p = 0; p < 2; p++) {
    const int s = t + p * 256;
    const int rr = s & 127, g = s >> 7;
    *(uint4*)(Xhi + obase + (size_t)s * 8) = *(const uint4*)&LHi[rr * 40 + g * 8];
    *(uint4*)(Xlo + obase + (size_t)s * 8) = *(const uint4*)&LLo[rr * 40 + g * 8];
  }
}

// ---------------------------------------------------------------------------
// Projection via MFMA. E = exp(2*(X @ W + bias)).
// 64x64 tile, 256 thr = 4 waves, 12 MFMA/K-step, BK=32. 3-buffer staging in
// one 48KB SMEM block (counted s_waitcnt vmcnt(4) + raw s_barrier, never
// drained in-loop); transpose buffer T ALIASES the staging LDS (dead after
// K-loop) -> 48KB total -> 3 blocks/CU. grid (8,68) XCD-swizzled.
// ---------------------------------------------------------------------------
__global__ __launch_bounds__(256) void proj_mfma(
    const unsigned short* __restrict__ Xhi, const unsigned short* __restrict__ Xlo,
    const unsigned short* __restrict__ Bhi, const unsigned short* __restrict__ Blo,
    const float* __restrict__ bk, const float* __restrict__ bq,
    float* __restrict__ EkT, float* __restrict__ Eq) {
  __shared__ __align__(16) unsigned short SMEM[3 * 8192];  // 48KB
  // buffer rb: Ahi @ rb*8192, Alo @ +2048, Bhi @ +4096, Blo @ +6144 (ushorts)

  const int bid = blockIdx.y * 8 + blockIdx.x;
  int ct, rt;
  if (bid < 512) {
    ct = (bid >> 3) & 7;
    rt = (bid & 7) + 8 * (bid >> 6);
  } else {
    const int tb = bid - 512;
    ct = tb >> 2;
    rt = 64 + (tb & 3);
  }

  const int mat = (rt >= 64) ? 1 : 0;
  const float* bias = mat ? bq : bk;

  const int t = threadIdx.x;
  const int rt128 = rt >> 1, hhalf = rt & 1;
  const int ga_slot = ((t >> 6) << 7) + (hhalf << 6) + (t & 63);
  const unsigned short* gah = Xhi + ((size_t)(rt128 * 16) * 512 + ga_slot) * 8;
  const unsigned short* gal = Xlo + ((size_t)(rt128 * 16) * 512 + ga_slot) * 8;
  const unsigned short* gbh = Bhi + (((size_t)(mat * 8 + ct) * 16) * 256 + t) * 8;
  const unsigned short* gbl = Blo + (((size_t)(mat * 8 + ct) * 16) * 256 + t) * 8;

  auto stage = [&](int buf, int kt2) {
    unsigned short* base = SMEM + buf * 8192;
    glds16(gah + (size_t)kt2 * 512 * 8, base + t * 8);
    glds16(gal + (size_t)kt2 * 512 * 8, base + 2048 + t * 8);
    glds16(gbh + (size_t)kt2 * 256 * 8, base + 4096 + t * 8);
    glds16(gbl + (size_t)kt2 * 256 * 8, base + 6144 + t * 8);
  };

  const int l = t & 63, lg = l >> 4, lr = l & 15;
  const int wv = t >> 6, wm = wv >> 1, wn = wv & 1;
  const int oa0 = (lg * 64 + wm * 32 + lr) * 8;
  const int ob0 = (lg * 64 + wn * 32 + lr) * 8;

  f32x4 acc[2][2];
#pragma unroll
  for (int m = 0; m < 2; m++)
#pragma unroll
    for (int n = 0; n < 2; n++) acc[m][n] = {0.f, 0.f, 0.f, 0.f};

  stage(0, 0);
  stage(1, 1);

#pragma unroll
  for (int kt2 = 0; kt2 < 16; kt2++) {
    if (kt2 < 15) asm volatile("s_waitcnt vmcnt(4)" ::: "memory");
    else          asm volatile("s_waitcnt vmcnt(0)" ::: "memory");
    __builtin_amdgcn_s_barrier();
    __builtin_amdgcn_sched_barrier(0);

    const unsigned short* base = SMEM + (kt2 % 3) * 8192;
    bf16x8 ah[2], al[2], bh[2], bl[2];
#pragma unroll
    for (int m = 0; m < 2; m++) {
      ah[m] = *(const bf16x8*)(base + oa0 + m * 128);
      al[m] = *(const bf16x8*)(base + 2048 + oa0 + m * 128);
    }
#pragma unroll
    for (int n = 0; n < 2; n++) {
      bh[n] = *(const bf16x8*)(base + 4096 + ob0 + n * 128);
      bl[n] = *(const bf16x8*)(base + 6144 + ob0 + n * 128);
    }
    if (kt2 < 14) stage((kt2 + 2) % 3, kt2 + 2);  // overlaps MFMAs below
#pragma unroll
    for (int m = 0; m < 2; m++)
#pragma unroll
      for (int n = 0; n < 2; n++) {
        acc[m][n] = __builtin_amdgcn_mfma_f32_16x16x32_bf16(ah[m], bh[n], acc[m][n], 0, 0, 0);
        acc[m][n] = __builtin_amdgcn_mfma_f32_16x16x32_bf16(al[m], bh[n], acc[m][n], 0, 0, 0);
        acc[m][n] = __builtin_amdgcn_mfma_f32_16x16x32_bf16(ah[m], bl[n], acc[m][n], 0, 0, 0);
      }
    __builtin_amdgcn_sched_barrier(0);
  }

  const int colL = wn * 32 + lr;
  const int col0 = ct * 64 + colL;
  const float b0 = bias[col0];
  const float b1 = bias[col0 + 16];

  if (mat == 0) {
    __syncthreads();  // staging LDS dead everywhere -> safe to alias as T
    float (*T)[65] = (float(*)[65])SMEM;  // 64x65 f32 = 16.6KB < 48KB
#pragma unroll
    for (int m = 0; m < 2; m++) {
      const int row0 = wm * 32 + m * 16 + lg * 4;
#pragma unroll
      for (int jj = 0; jj < 4; jj++) {
        T[row0 + jj][colL]      = __expf(2.f * (acc[m][0][jj] + b0));
        T[row0 + jj][colL + 16] = __expf(2.f * (acc[m][1][jj] + b1));
      }
    }
    __syncthreads();
    const int sl = t & 63;
    const int cb = (t >> 6) * 16;
    const int R = rt * 64 + sl;
    const int bb = R >> 10, ss = R & 1023;
    float* outp = EkT + ((size_t)(bb * kH + ct * 64)) * kS + ss;
#pragma unroll
    for (int i = 0; i < 16; i++)
      outp[(size_t)(cb + i) * kS] = T[sl][cb + i];
  } else {
    float* Y = Eq + (size_t)(rt - 64) * 64 * kH;
#pragma unroll
    for (int m = 0; m < 2; m++) {
      const int row0 = wm * 32 + m * 16 + lg * 4;
#pragma unroll
      for (int jj = 0; jj < 4; jj++) {
        float* y = Y + (size_t)(row0 + jj) * kH;
        y[col0]      = __expf(2.f * (acc[m][0][jj] + b0));
        y[col0 + 16] = __expf(2.f * (acc[m][1][jj] + b1));
      }
    }
  }
}

// ---------------------------------------------------------------------------
// Scores (partials) -> sraw4[hq][bq][s].  No LDS, no barriers.
// 256 thr = 4 waves/block, grid 2048; u = bid*4 + wave. The 4 waves of a
// block are the 4 h-quarters of one (b, q-pair, s-tile) -> shared Eq rows.
// ~32 waves/CU (was 16 at 128-thr blocks, Occ 49%).
// partial = wsum4[hq] - 2 * sum we_h * rcp(1 + Eq*EkT), rcps paired.
// ---------------------------------------------------------------------------
__global__ __launch_bounds__(256) void score_kernel(
    const float* __restrict__ Eq, const float* __restrict__ EkT,
    const float* __restrict__ wsum4, const float* __restrict__ we,
    float* __restrict__ sraw4) {
  const int t = threadIdx.x, lane = t & 63;
  const int wvu = __builtin_amdgcn_readfirstlane(t >> 6);
  const int u = blockIdx.x * 4 + wvu;
  const int hq = u & 3, st = (u >> 2) & 15, qp = (u >> 6) & 31, b = u >> 11;
  const int s = st * 64 + lane;
  const int q0g = b * kQ + qp * 2;
  const int h0 = hq * 128;

  const float4* w4 = (const float4*)(we + h0);
  const float4* qa4 = (const float4*)(Eq + (size_t)q0g * kH + h0);
  const float4* qb4 = (const float4*)(Eq + (size_t)(q0g + 1) * kH + h0);
  const float* ek = EkT + ((size_t)(b * kH + h0)) * kS + s;
  const float wsum = wsum4[hq];

  float accA = 0.f, accB = 0.f;
#pragma unroll 4
  for (int g = 0; g < 32; g++) {
    const float4 w = w4[g];
    const float4 qa = qa4[g];
    const float4 qb = qb4[g];
    const float e0 = ek[(size_t)(4 * g + 0) * kS];
    const float e1 = ek[(size_t)(4 * g + 1) * kS];
    const float e2 = ek[(size_t)(4 * g + 2) * kS];
    const float e3 = ek[(size_t)(4 * g + 3) * kS];
    {
      float a1 = fmaf(qa.x, e0, 1.f), c1 = fmaf(qa.y, e1, 1.f);
      accA = fmaf(fmaf(w.y, a1, w.x * c1), __builtin_amdgcn_rcpf(a1 * c1), accA);
      float a2 = fmaf(qa.z, e2, 1.f), c2 = fmaf(qa.w, e3, 1.f);
      accA = fmaf(fmaf(w.w, a2, w.z * c2), __builtin_amdgcn_rcpf(a2 * c2), accA);
    }
    {
      float a1 = fmaf(qb.x, e0, 1.f), c1 = fmaf(qb.y, e1, 1.f);
      accB = fmaf(fmaf(w.y, a1, w.x * c1), __builtin_amdgcn_rcpf(a1 * c1), accB);
      float a2 = fmaf(qb.z, e2, 1.f), c2 = fmaf(qb.w, e3, 1.f);
      accB = fmaf(fmaf(w.w, a2, w.z * c2), __builtin_amdgcn_rcpf(a2 * c2), accB);
    }
  }

  float* plane = sraw4 + (size_t)hq * kB * kQ * kS;
  plane[(size_t)(q0g + 0) * kS + s] = fmaf(-2.f, accA, wsum);
  plane[(size_t)(q0g + 1) * kS + s] = fmaf(-2.f, accB, wsum);
}

// ---------------------------------------------------------------------------
// Fused softmax + context + reduce (unchanged from R9).
// ---------------------------------------------------------------------------
__global__ __launch_bounds__(256) void ctx_fused(
    const float* __restrict__ sraw4, const float* __restrict__ value,
    float* __restrict__ wout, float* __restrict__ ctx) {
  __shared__ __align__(16) float wt[4][1024];
  __shared__ __align__(16) float parts[4][4][128];
  const int bid = blockIdx.x;
  const int qc = bid >> 4, b = (bid >> 2) & 3, hc = bid & 3;
  const int t = threadIdx.x, wv = t >> 6, lane = t & 63;
  const int grow = b * kQ + qc * 4 + wv;

  const size_t plane = (size_t)kB * kQ * kS / 4;
  const float4* r0 = (const float4*)(sraw4) + (size_t)grow * (kS / 4);
  const float4* r1 = r0 + plane;
  const float4* r2 = r1 + plane;
  const float4* r3 = r2 + plane;
  float4 v[4];
#pragma unroll
  for (int j = 0; j < 4; j++) {
    const int idx = lane + 64 * j;
    float4 p0 = r0[idx], p1 = r1[idx], p2 = r2[idx], p3 = r3[idx];
    v[j].x = (p0.x + p1.x) + (p2.x + p3.x);
    v[j].y = (p0.y + p1.y) + (p2.y + p3.y);
    v[j].z = (p0.z + p1.z) + (p2.z + p3.z);
    v[j].w = (p0.w + p1.w) + (p2.w + p3.w);
  }
  float m = -1e30f;
#pragma unroll
  for (int j = 0; j < 4; j++)
    m = fmaxf(m, fmaxf(fmaxf(v[j].x, v[j].y), fmaxf(v[j].z, v[j].w)));
#pragma unroll
  for (int off = 32; off; off >>= 1) m = fmaxf(m, __shfl_xor(m, off));
  float sum = 0.f;
#pragma unroll
  for (int j = 0; j < 4; j++) {
    v[j].x = __expf(v[j].x - m); v[j].y = __expf(v[j].y - m);
    v[j].z = __expf(v[j].z - m); v[j].w = __expf(v[j].w - m);
    sum += v[j].x + v[j].y + v[j].z + v[j].w;
  }
#pragma unroll
  for (int off = 32; off; off >>= 1) sum += __shfl_xor(sum, off);
  const float inv = 1.f / sum;
  float4* wrow = (float4*)&wt[wv][0];
  float4* gw = (float4*)(wout + (size_t)grow * kS);
#pragma unroll
  for (int j = 0; j < 4; j++) {
    v[j].x *= inv; v[j].y *= inv; v[j].z *= inv; v[j].w *= inv;
    wrow[lane + 64 * j] = v[j];
    if (hc == 0) gw[lane + 64 * j] = v[j];
  }
  __syncthreads();

  const float* vbase =
      value + ((size_t)b * kS + wv * 256) * kH + hc * 128 + lane * 2;
  float2 acc[4];
#pragma unroll
  for (int q = 0; q < 4; q++) acc[q] = {0.f, 0.f};
#pragma unroll 2
  for (int s4 = 0; s4 < 64; s4++) {
    float4 wq[4];
#pragma unroll
    for (int q = 0; q < 4; q++)
      wq[q] = *(const float4*)&wt[q][wv * 256 + s4 * 4];
#pragma unroll
    for (int uu = 0; uu < 4; uu++) {
      const float2 vv = *(const float2*)(vbase + (size_t)(s4 * 4 + uu) * kH);
      const float w0 = ((const float*)&wq[0])[uu];
      const float w1 = ((const float*)&wq[1])[uu];
      const float w2 = ((const float*)&wq[2])[uu];
      const float w3 = ((const float*)&wq[3])[uu];
      acc[0].x = fmaf(w0, vv.x, acc[0].x); acc[0].y = fmaf(w0, vv.y, acc[0].y);
      acc[1].x = fmaf(w1, vv.x, acc[1].x); acc[1].y = fmaf(w1, vv.y, acc[1].y);
      acc[2].x = fmaf(w2, vv.x, acc[2].x); acc[2].y = fmaf(w2, vv.y, acc[2].y);
      acc[3].x = fmaf(w3, vv.x, acc[3].x); acc[3].y = fmaf(w3, vv.y, acc[3].y);
    }
  }
#pragma unroll
  for (int q = 0; q < 4; q++)
    *(float2*)&parts[wv][q][lane * 2] = acc[q];
  __syncthreads();

  const int q = t >> 6, hp = t & 63;
  float2 r = {0.f, 0.f};
#pragma unroll
  for (int w = 0; w < 4; w++) {
    const float2 p2 = *(const float2*)&parts[w][q][hp * 2];
    r.x += p2.x; r.y += p2.y;
  }
  *(float2*)(ctx + (size_t)(b * kQ + qc * 4 + q) * kH + hc * 128 + hp * 2) = r;
}

extern "C" void kernel_launch(void* const* d_in, const int* in_sizes, int n_in,
                              void* d_out, int out_size, void* d_ws,
                              size_t ws_size, hipStream_t stream) {
  const float* query = (const float*)d_in[0];
  const float* key_  = (const float*)d_in[1];
  const float* value = (const float*)d_in[2];
  const float* Wq    = (const float*)d_in[3];
  const float* bq    = (const float*)d_in[4];
  const float* Wk    = (const float*)d_in[5];
  const float* bk    = (const float*)d_in[6];
  const float* we    = (const float*)d_in[7];
  // be (d_in[8]) cancels in softmax.

  float* ctx  = (float*)d_out;                         // [256*512]
  float* wout = (float*)d_out + (size_t)kB * kQ * kH;  // [256*1024]

  float* Eq    = (float*)d_ws;                          // 512 KB
  float* sraw4 = Eq + (size_t)kB * kQ * kH;             // 4 MB
  unsigned short* Bhi =
      (unsigned short*)((char*)d_ws + (size_t)(kB * kQ * kH + kB * kS * kH) * 4);
  unsigned short* Blo = Bhi + (size_t)2 * 8 * 16 * 256 * 8;  // +1MB
  unsigned short* Xhi = Blo + (size_t)2 * 8 * 16 * 256 * 8;  // +1MB
  unsigned short* Xlo = Xhi + (size_t)34 * 16 * 512 * 8;     // +4.25MB
  float* EkT = (float*)(Xlo + (size_t)34 * 16 * 512 * 8);    // +4.25MB -> 8MB
  float* wsum4 = EkT + (size_t)4 * 512 * 1024;               // 16B

  convert_all<<<801, 256, 0, stream>>>(Wk, Wq, key_, query, we, Bhi, Blo, Xhi,
                                       Xlo, wsum4);
  proj_mfma<<<dim3(8, 68), 256, 0, stream>>>(Xhi, Xlo, Bhi, Blo, bk, bq, EkT, Eq);
  score_kernel<<<2048, 256, 0, stream>>>(Eq, EkT, wsum4, we, sraw4);
  ctx_fused<<<256, 256, 0, stream>>>(sraw4, value, wout, ctx);
}

// Round 13
// 132.532 us; speedup vs baseline: 1.5767x; 1.0170x over previous
//
#include <hip/hip_runtime.h>

// SoftAttention: B=4, Q=64, S=1024, H=512, fp32.
// out = [context (B*Q*H)] ++ [weights (B*Q*S)]
// ws: Eq [256*512]f32 @0; sraw4 [4][256][1024]f32 @+512KB;
//     Bhi/Blo @+8.5MB (1MB each); Xhi/Xlo @+10.5MB (4.25MB each);
//     EkT4 [4][128][1024][4]f32 @+19MB (8MB, h-quad packed); wsum4 [4]f32.
//
// R12 measured: 134.8us total; score ~13-14us, L2-BW-bound (268MB EkT
//   re-reads), not latency-bound (256-thr occupancy fix underdelivered).
// R13: (a) score 4 q-rows/wave (EkT traffic 268->134MB; 4 indep q-chains
//   ILP); (b) EkT h-quad-packed layout [b][h/4][s][4]: score's 4 stride-4KB
//   dword loads/g -> 1 coalesced float4 load; proj epilogue scatter-dwords ->
//   4 coalesced float4 stores. Same values + summation order (bit-identical).

constexpr int kB = 4;
constexpr int kQ = 64;
constexpr int kS = 1024;
constexpr int kH = 512;

typedef short bf16x8 __attribute__((ext_vector_type(8)));
typedef float f32x4 __attribute__((ext_vector_type(4)));

__device__ __forceinline__ unsigned bf16rtn_bits(float x) {
  unsigned u = __float_as_uint(x);
  u += 0x7FFFu + ((u >> 16) & 1u);
  return u;  // hi bf16 = u>>16; its f32 bits = u & 0xFFFF0000
}

__device__ __forceinline__ void glds16(const void* g, void* l) {
  __builtin_amdgcn_global_load_lds(
      (__attribute__((address_space(1))) void*)(g),
      (__attribute__((address_space(3))) void*)(l), 16, 0, 0);
}

// ---------------------------------------------------------------------------
// Fused converter. Blocks 0..255: W -> Bhi/Blo. Blocks 256..799: X -> Xhi/Xlo.
// Block 800: wsum4[hq] = sum of we over h-quarter hq.
// ---------------------------------------------------------------------------
__global__ __launch_bounds__(256) void convert_all(
    const float* __restrict__ Wk, const float* __restrict__ Wq,
    const float* __restrict__ key_, const float* __restrict__ query,
    const float* __restrict__ we,
    unsigned short* __restrict__ Bhi, unsigned short* __restrict__ Blo,
    unsigned short* __restrict__ Xhi, unsigned short* __restrict__ Xlo,
    float* __restrict__ wsum4) {
  __shared__ __align__(16) unsigned short LHi[128 * 40];
  __shared__ __align__(16) unsigned short LLo[128 * 40];
  const int bid = blockIdx.x;
  const int t = threadIdx.x;
  if (bid == 800) {
    const int w = t >> 6, ln = t & 63;
    float v = we[w * 128 + ln] + we[w * 128 + 64 + ln];
#pragma unroll
    for (int off = 32; off; off >>= 1) v += __shfl_xor(v, off);
    if (ln == 0) wsum4[w] = v;
    return;
  }
  if (bid < 256) {
    const int gid = bid * 256 + t;
    const int c = gid & 63;
    const int g = (gid >> 6) & 3;
    const int kt = (gid >> 8) & 15;
    const int ct = (gid >> 12) & 7;
    const int mat = gid >> 15;
    const float* W = mat ? Wq : Wk;
    const float* src = W + (size_t)(kt * 32 + g * 8) * kH + ct * 64 + c;
    bf16x8 hv, lv;
#pragma unroll
    for (int j = 0; j < 8; j++) {
      float x = src[(size_t)j * kH];
      unsigned u = bf16rtn_bits(x);
      float hf = __uint_as_float(u & 0xFFFF0000u);
      unsigned v = bf16rtn_bits(x - hf);
      hv[j] = (short)(u >> 16);
      lv[j] = (short)(v >> 16);
    }
    *(bf16x8*)(Bhi + (size_t)gid * 8) = hv;
    *(bf16x8*)(Blo + (size_t)gid * 8) = lv;
    return;
  }
  const int xb = bid - 256;
  const int kt = xb & 15;
  const int rt = xb >> 4;  // 0..33
  const float* X = (rt < 32) ? (key_ + (size_t)rt * 128 * kH)
                             : (query + (size_t)(rt - 32) * 128 * kH);
  const int r = t >> 1, c0 = (t & 1) * 16;
  const float* src = X + (size_t)r * kH + kt * 32 + c0;
  bf16x8 hv0, hv1, lv0, lv1;
#pragma unroll
  for (int i = 0; i < 16; i++) {
    float x = src[i];
    unsigned u = bf16rtn_bits(x);
    float hf = __uint_as_float(u & 0xFFFF0000u);
    unsigned v = bf16rtn_bits(x - hf);
    if (i < 8) { hv0[i] = (short)(u >> 16); lv0[i] = (short)(v >> 16); }
    else       { hv1[i - 8] = (short)(u >> 16); lv1[i - 8] = (short)(v >> 16); }
  }
  *(bf16x8*)&LHi[r * 40 + c0] = hv0;
  *(bf16x8*)&LHi[r * 40 + c0 + 8] = hv1;
  *(bf16x8*)&LLo[r * 40 + c0] = lv0;
  *(bf16x8*)&LLo[r * 40 + c0 + 8] = lv1;
  __syncthreads();
  const size_t obase = (size_t)(rt * 16 + kt) * 512 * 8;
#pragma unroll
  for (int p = 0; p < 2; p++) {
    const int s = t + p * 256;
    const int rr = s & 127, g = s >> 7;
    *(uint4*)(Xhi + obase + (size_t)s * 8) = *(const uint4*)&LHi[rr * 40 + g * 8];
    *(uint4*)(Xlo + obase + (size_t)s * 8) = *(const uint4*)&LLo[rr * 40 + g * 8];
  }
}

// ---------------------------------------------------------------------------
// Projection via MFMA. E = exp(2*(X @ W + bias)).
// 64x64 tile, 256 thr = 4 waves, 12 MFMA/K-step, BK=32. 3-buffer staging in
// one 48KB SMEM block (counted s_waitcnt vmcnt(4) + raw s_barrier, never
// drained in-loop); transpose buffer T ALIASES the staging LDS.
// mat==0: epilogue writes EkT4 [b][h/4][s][4] via coalesced float4 stores.
// grid (8,68) XCD-swizzled.
// ---------------------------------------------------------------------------
__global__ __launch_bounds__(256) void proj_mfma(
    const unsigned short* __restrict__ Xhi, const unsigned short* __restrict__ Xlo,
    const unsigned short* __restrict__ Bhi, const unsigned short* __restrict__ Blo,
    const float* __restrict__ bk, const float* __restrict__ bq,
    float* __restrict__ EkT4, float* __restrict__ Eq) {
  __shared__ __align__(16) unsigned short SMEM[3 * 8192];  // 48KB
  // buffer rb: Ahi @ rb*8192, Alo @ +2048, Bhi @ +4096, Blo @ +6144 (ushorts)

  const int bid = blockIdx.y * 8 + blockIdx.x;
  int ct, rt;
  if (bid < 512) {
    ct = (bid >> 3) & 7;
    rt = (bid & 7) + 8 * (bid >> 6);
  } else {
    const int tb = bid - 512;
    ct = tb >> 2;
    rt = 64 + (tb & 3);
  }

  const int mat = (rt >= 64) ? 1 : 0;
  const float* bias = mat ? bq : bk;

  const int t = threadIdx.x;
  const int rt128 = rt >> 1, hhalf = rt & 1;
  const int ga_slot = ((t >> 6) << 7) + (hhalf << 6) + (t & 63);
  const unsigned short* gah = Xhi + ((size_t)(rt128 * 16) * 512 + ga_slot) * 8;
  const unsigned short* gal = Xlo + ((size_t)(rt128 * 16) * 512 + ga_slot) * 8;
  const unsigned short* gbh = Bhi + (((size_t)(mat * 8 + ct) * 16) * 256 + t) * 8;
  const unsigned short* gbl = Blo + (((size_t)(mat * 8 + ct) * 16) * 256 + t) * 8;

  auto stage = [&](int buf, int kt2) {
    unsigned short* base = SMEM + buf * 8192;
    glds16(gah + (size_t)kt2 * 512 * 8, base + t * 8);
    glds16(gal + (size_t)kt2 * 512 * 8, base + 2048 + t * 8);
    glds16(gbh + (size_t)kt2 * 256 * 8, base + 4096 + t * 8);
    glds16(gbl + (size_t)kt2 * 256 * 8, base + 6144 + t * 8);
  };

  const int l = t & 63, lg = l >> 4, lr = l & 15;
  const int wv = t >> 6, wm = wv >> 1, wn = wv & 1;
  const int oa0 = (lg * 64 + wm * 32 + lr) * 8;
  const int ob0 = (lg * 64 + wn * 32 + lr) * 8;

  f32x4 acc[2][2];
#pragma unroll
  for (int m = 0; m < 2; m++)
#pragma unroll
    for (int n = 0; n < 2; n++) acc[m][n] = {0.f, 0.f, 0.f, 0.f};

  stage(0, 0);
  stage(1, 1);

#pragma unroll
  for (int kt2 = 0; kt2 < 16; kt2++) {
    if (kt2 < 15) asm volatile("s_waitcnt vmcnt(4)" ::: "memory");
    else          asm volatile("s_waitcnt vmcnt(0)" ::: "memory");
    __builtin_amdgcn_s_barrier();
    __builtin_amdgcn_sched_barrier(0);

    const unsigned short* base = SMEM + (kt2 % 3) * 8192;
    bf16x8 ah[2], al[2], bh[2], bl[2];
#pragma unroll
    for (int m = 0; m < 2; m++) {
      ah[m] = *(const bf16x8*)(base + oa0 + m * 128);
      al[m] = *(const bf16x8*)(base + 2048 + oa0 + m * 128);
    }
#pragma unroll
    for (int n = 0; n < 2; n++) {
      bh[n] = *(const bf16x8*)(base + 4096 + ob0 + n * 128);
      bl[n] = *(const bf16x8*)(base + 6144 + ob0 + n * 128);
    }
    if (kt2 < 14) stage((kt2 + 2) % 3, kt2 + 2);  // overlaps MFMAs below
#pragma unroll
    for (int m = 0; m < 2; m++)
#pragma unroll
      for (int n = 0; n < 2; n++) {
        acc[m][n] = __builtin_amdgcn_mfma_f32_16x16x32_bf16(ah[m], bh[n], acc[m][n], 0, 0, 0);
        acc[m][n] = __builtin_amdgcn_mfma_f32_16x16x32_bf16(al[m], bh[n], acc[m][n], 0, 0, 0);
        acc[m][n] = __builtin_amdgcn_mfma_f32_16x16x32_bf16(ah[m], bl[n], acc[m][n], 0, 0, 0);
      }
    __builtin_amdgcn_sched_barrier(0);
  }

  const int colL = wn * 32 + lr;
  const int col0 = ct * 64 + colL;
  const float b0 = bias[col0];
  const float b1 = bias[col0 + 16];

  if (mat == 0) {
    __syncthreads();  // staging LDS dead everywhere -> safe to alias as T
    float (*T)[65] = (float(*)[65])SMEM;  // 64x65 f32 = 16.6KB < 48KB
#pragma unroll
    for (int m = 0; m < 2; m++) {
      const int row0 = wm * 32 + m * 16 + lg * 4;
#pragma unroll
      for (int jj = 0; jj < 4; jj++) {
        T[row0 + jj][colL]      = __expf(2.f * (acc[m][0][jj] + b0));
        T[row0 + jj][colL + 16] = __expf(2.f * (acc[m][1][jj] + b1));
      }
    }
    __syncthreads();
    const int sl = t & 63;          // s within tile (lane -> coalesced)
    const int cb = (t >> 6) * 16;   // h block of 16 (quad-aligned)
    const int R = rt * 64 + sl;
    const int bb = R >> 10, ss = R & 1023;
    // EkT4[b][hquad][s][4]: float4 stores, lanes consecutive in ss.
    float* outp =
        EkT4 + (((size_t)(bb * 128 + ((ct * 64 + cb) >> 2))) * 1024 + ss) * 4;
#pragma unroll
    for (int j = 0; j < 4; j++) {
      float4 v4 = {T[sl][cb + 4 * j + 0], T[sl][cb + 4 * j + 1],
                   T[sl][cb + 4 * j + 2], T[sl][cb + 4 * j + 3]};
      *(float4*)(outp + (size_t)j * 1024 * 4) = v4;
    }
  } else {
    float* Y = Eq + (size_t)(rt - 64) * 64 * kH;
#pragma unroll
    for (int m = 0; m < 2; m++) {
      const int row0 = wm * 32 + m * 16 + lg * 4;
#pragma unroll
      for (int jj = 0; jj < 4; jj++) {
        float* y = Y + (size_t)(row0 + jj) * kH;
        y[col0]      = __expf(2.f * (acc[m][0][jj] + b0));
        y[col0 + 16] = __expf(2.f * (acc[m][1][jj] + b1));
      }
    }
  }
}

// ---------------------------------------------------------------------------
// Scores (partials) -> sraw4[hq][bq][s].  No LDS, no barriers.
// Unit = wave = (b, 4 q-rows, 64 s, 128 h-quarter): 4096 waves = 1024 blocks
// x 256 thr; u = bid*4 + wave. EkT4 traffic 134MB (was 268 at 2q), one
// coalesced float4 load per 4 h (was 4 stride-4KB dwords).
// partial = wsum4[hq] - 2 * sum we_h * rcp(1 + Eq*Ek), rcps paired.
// ---------------------------------------------------------------------------
__global__ __launch_bounds__(256) void score_kernel(
    const float* __restrict__ Eq, const float* __restrict__ EkT4,
    const float* __restrict__ wsum4, const float* __restrict__ we,
    float* __restrict__ sraw4) {
  const int t = threadIdx.x, lane = t & 63;
  const int wvu = __builtin_amdgcn_readfirstlane(t >> 6);
  const int u = blockIdx.x * 4 + wvu;
  const int hq = u & 3, st = (u >> 2) & 15, qo = (u >> 6) & 15, b = u >> 10;
  const int s = st * 64 + lane;
  const int q0g = b * kQ + qo * 4;
  const int h0 = hq * 128;

  const float4* w4 = (const float4*)(we + h0);
  const float4* qa4 = (const float4*)(Eq + (size_t)(q0g + 0) * kH + h0);
  const float4* qb4 = (const float4*)(Eq + (size_t)(q0g + 1) * kH + h0);
  const float4* qc4 = (const float4*)(Eq + (size_t)(q0g + 2) * kH + h0);
  const float4* qd4 = (const float4*)(Eq + (size_t)(q0g + 3) * kH + h0);
  const float* ek = EkT4 + ((size_t)(b * 128 + (h0 >> 2)) * 1024 + s) * 4;
  const float wsum = wsum4[hq];

  float acc0 = 0.f, acc1 = 0.f, acc2 = 0.f, acc3 = 0.f;
#pragma unroll 4
  for (int g = 0; g < 32; g++) {
    const float4 e = *(const float4*)(ek + (size_t)g * 4096);
    const float4 w = w4[g];
    const float4 qa = qa4[g];
    const float4 qb = qb4[g];
    const float4 qc = qc4[g];
    const float4 qd = qd4[g];
#define SCORE_PAIR(accv, qv)                                                  \
  {                                                                           \
    float a1 = fmaf(qv.x, e.x, 1.f), c1 = fmaf(qv.y, e.y, 1.f);               \
    accv = fmaf(fmaf(w.y, a1, w.x * c1), __builtin_amdgcn_rcpf(a1 * c1), accv);\
    float a2 = fmaf(qv.z, e.z, 1.f), c2 = fmaf(qv.w, e.w, 1.f);               \
    accv = fmaf(fmaf(w.w, a2, w.z * c2), __builtin_amdgcn_rcpf(a2 * c2), accv);\
  }
    SCORE_PAIR(acc0, qa)
    SCORE_PAIR(acc1, qb)
    SCORE_PAIR(acc2, qc)
    SCORE_PAIR(acc3, qd)
#undef SCORE_PAIR
  }

  float* plane = sraw4 + (size_t)hq * kB * kQ * kS;
  plane[(size_t)(q0g + 0) * kS + s] = fmaf(-2.f, acc0, wsum);
  plane[(size_t)(q0g + 1) * kS + s] = fmaf(-2.f, acc1, wsum);
  plane[(size_t)(q0g + 2) * kS + s] = fmaf(-2.f, acc2, wsum);
  plane[(size_t)(q0g + 3) * kS + s] = fmaf(-2.f, acc3, wsum);
}

// ---------------------------------------------------------------------------
// Fused softmax + context + reduce (unchanged from R9).
// ---------------------------------------------------------------------------
__global__ __launch_bounds__(256) void ctx_fused(
    const float* __restrict__ sraw4, const float* __restrict__ value,
    float* __restrict__ wout, float* __restrict__ ctx) {
  __shared__ __align__(16) float wt[4][1024];
  __shared__ __align__(16) float parts[4][4][128];
  const int bid = blockIdx.x;
  const int qc = bid >> 4, b = (bid >> 2) & 3, hc = bid & 3;
  const int t = threadIdx.x, wv = t >> 6, lane = t & 63;
  const int grow = b * kQ + qc * 4 + wv;

  const size_t plane = (size_t)kB * kQ * kS / 4;
  const float4* r0 = (const float4*)(sraw4) + (size_t)grow * (kS / 4);
  const float4* r1 = r0 + plane;
  const float4* r2 = r1 + plane;
  const float4* r3 = r2 + plane;
  float4 v[4];
#pragma unroll
  for (int j = 0; j < 4; j++) {
    const int idx = lane + 64 * j;
    float4 p0 = r0[idx], p1 = r1[idx], p2 = r2[idx], p3 = r3[idx];
    v[j].x = (p0.x + p1.x) + (p2.x + p3.x);
    v[j].y = (p0.y + p1.y) + (p2.y + p3.y);
    v[j].z = (p0.z + p1.z) + (p2.z + p3.z);
    v[j].w = (p0.w + p1.w) + (p2.w + p3.w);
  }
  float m = -1e30f;
#pragma unroll
  for (int j = 0; j < 4; j++)
    m = fmaxf(m, fmaxf(fmaxf(v[j].x, v[j].y), fmaxf(v[j].z, v[j].w)));
#pragma unroll
  for (int off = 32; off; off >>= 1) m = fmaxf(m, __shfl_xor(m, off));
  float sum = 0.f;
#pragma unroll
  for (int j = 0; j < 4; j++) {
    v[j].x = __expf(v[j].x - m); v[j].y = __expf(v[j].y - m);
    v[j].z = __expf(v[j].z - m); v[j].w = __expf(v[j].w - m);
    sum += v[j].x + v[j].y + v[j].z + v[j].w;
  }
#pragma unroll
  for (int off = 32; off; off >>= 1) sum += __shfl_xor(sum, off);
  const float inv = 1.f / sum;
  float4* wrow = (float4*)&wt[wv][0];
  float4* gw = (float4*)(wout + (size_t)grow * kS);
#pragma unroll
  for (int j = 0; j < 4; j++) {
    v[j].x *= inv; v[j].y *= inv; v[j].z *= inv; v[j].w *= inv;
    wrow[lane + 64 * j] = v[j];
    if (hc == 0) gw[lane + 64 * j] = v[j];
  }
  __syncthreads();

  const float* vbase =
      value + ((size_t)b * kS + wv * 256) * kH + hc * 128 + lane * 2;
  float2 acc[4];
#pragma unroll
  for (int q = 0; q < 4; q++) acc[q] = {0.f, 0.f};
#pragma unroll 2
  for (int s4 = 0; s4 < 64; s4++) {
    float4 wq[4];
#pragma unroll
    for (int q = 0; q < 4; q++)
      wq[q] = *(const float4*)&wt[q][wv * 256 + s4 * 4];
#pragma unroll
    for (int uu = 0; uu < 4; uu++) {
      const float2 vv = *(const float2*)(vbase + (size_t)(s4 * 4 + uu) * kH);
      const float w0 = ((const float*)&wq[0])[uu];
      const float w1 = ((const float*)&wq[1])[uu];
      const float w2 = ((const float*)&wq[2])[uu];
      const float w3 = ((const float*)&wq[3])[uu];
      acc[0].x = fmaf(w0, vv.x, acc[0].x); acc[0].y = fmaf(w0, vv.y, acc[0].y);
      acc[1].x = fmaf(w1, vv.x, acc[1].x); acc[1].y = fmaf(w1, vv.y, acc[1].y);
      acc[2].x = fmaf(w2, vv.x, acc[2].x); acc[2].y = fmaf(w2, vv.y, acc[2].y);
      acc[3].x = fmaf(w3, vv.x, acc[3].x); acc[3].y = fmaf(w3, vv.y, acc[3].y);
    }
  }
#pragma unroll
  for (int q = 0; q < 4; q++)
    *(float2*)&parts[wv][q][lane * 2] = acc[q];
  __syncthreads();

  const int q = t >> 6, hp = t & 63;
  float2 r = {0.f, 0.f};
#pragma unroll
  for (int w = 0; w < 4; w++) {
    const float2 p2 = *(const float2*)&parts[w][q][hp * 2];
    r.x += p2.x; r.y += p2.y;
  }
  *(float2*)(ctx + (size_t)(b * kQ + qc * 4 + q) * kH + hc * 128 + hp * 2) = r;
}

extern "C" void kernel_launch(void* const* d_in, const int* in_sizes, int n_in,
                              void* d_out, int out_size, void* d_ws,
                              size_t ws_size, hipStream_t stream) {
  const float* query = (const float*)d_in[0];
  const float* key_  = (const float*)d_in[1];
  const float* value = (const float*)d_in[2];
  const float* Wq    = (const float*)d_in[3];
  const float* bq    = (const float*)d_in[4];
  const float* Wk    = (const float*)d_in[5];
  const float* bk    = (const float*)d_in[6];
  const float* we    = (const float*)d_in[7];
  // be (d_in[8]) cancels in softmax.

  float* ctx  = (float*)d_out;                         // [256*512]
  float* wout = (float*)d_out + (size_t)kB * kQ * kH;  // [256*1024]

  float* Eq    = (float*)d_ws;                          // 512 KB
  float* sraw4 = Eq + (size_t)kB * kQ * kH;             // 4 MB
  unsigned short* Bhi =
      (unsigned short*)((char*)d_ws + (size_t)(kB * kQ * kH + kB * kS * kH) * 4);
  unsigned short* Blo = Bhi + (size_t)2 * 8 * 16 * 256 * 8;  // +1MB
  unsigned short* Xhi = Blo + (size_t)2 * 8 * 16 * 256 * 8;  // +1MB
  unsigned short* Xlo = Xhi + (size_t)34 * 16 * 512 * 8;     // +4.25MB
  float* EkT4 = (float*)(Xlo + (size_t)34 * 16 * 512 * 8);   // +4.25MB -> 8MB
  float* wsum4 = EkT4 + (size_t)4 * 512 * 1024;              // 16B

  convert_all<<<801, 256, 0, stream>>>(Wk, Wq, key_, query, we, Bhi, Blo, Xhi,
                                       Xlo, wsum4);
  proj_mfma<<<dim3(8, 68), 256, 0, stream>>>(Xhi, Xlo, Bhi, Blo, bk, bq, EkT4, Eq);
  score_kernel<<<1024, 256, 0, stream>>>(Eq, EkT4, wsum4, we, sraw4);
  ctx_fused<<<256, 256, 0, stream>>>(sraw4, value, wout, ctx);
}